// Round 18
// baseline (2169.625 us; speedup 1.0000x reference)
//
#include <hip/hip_runtime.h>

typedef unsigned int   uint;
typedef unsigned short ushort;
typedef unsigned long long u64;
typedef float f32x4 __attribute__((ext_vector_type(4)));
typedef short bf16x8 __attribute__((ext_vector_type(8)));   // 8 bf16 = 4 VGPRs
typedef uint  uint2v __attribute__((ext_vector_type(2)));

#define STR  88    // LDS row stride (shorts) for 64-col tiles
#define STR1 104   // LDS row stride (shorts) for 96-col padded pass-1 tiles

// RNE fp32 -> bf16 pair packed into one dword
__device__ __forceinline__ uint packbf2(float a, float b){
  uint ua=__float_as_uint(a); ua=(ua+0x7fffu+((ua>>16)&1u))>>16;
  uint ub=__float_as_uint(b); ub=(ub+0x7fffu+((ub>>16)&1u))>>16;
  return ua|(ub<<16);
}
__device__ __forceinline__ ushort bf1(float a){
  uint ua=__float_as_uint(a); return (ushort)((ua+0x7fffu+((ua>>16)&1u))>>16);
}

// ---------------------------------------------------------------- fused FPS + KNN
// r28: r27's overlap with the contention defect fixed. r27 measured fps
// stretched 758->1500us by its co-resident knn block (2 blocks/CU at 70KB).
// Fix 1: pad the LDS union to 84KB (>160/2) -> EVERY k_fk block gets an
// exclusive CU; the 16 fps blocks can never share with knn (or each other).
// Fix 2: stage-major knn ordering (stage, batch, chunk) so the first-
// dispatched knn blocks are the earliest-available work: each 128-query
// stage (released every ~95us by fps) is 512 blocks (~60us over 240 CUs)
// -> pipeline tracks fps, tail ~60-90us. Selection arithmetic untouched.
__global__ __launch_bounds__(256) void k_fk(const float* __restrict__ xyz,
                                            int* __restrict__ cent,
                                            float* __restrict__ oxyz,
                                            float* __restrict__ pxyz,
                                            ushort* __restrict__ kidx,
                                            int* __restrict__ flags){
  __shared__ __align__(16) char LU[86016];     // 84KB: forces 1 block/CU
  const int bid=blockIdx.x, tid=threadIdx.x, lane=tid&63, wave=tid>>6;
  const u64 SENT=~0ull;

  if (bid < 16){
    // ---------------- FPS (r26 body + progressive publication) ----------------
    __builtin_amdgcn_s_setprio(1);
    float (*sp)[4] = (float(*)[4])LU;            // 64 KB
    u64* rk  = (u64*)(LU + 65536);
    int* sel = (int*)(LU + 65600);               // 4 KB
    const int b = bid;
    const float* xb = xyz + (long)b*4096*3;
    float px[16], py[16], pz[16], pd[16];
#pragma unroll
    for (int j=0;j<16;j++){
      int n = tid + 256*j;
      float x=xb[n*3], y=xb[n*3+1], z=xb[n*3+2];
      sp[n][0]=x; sp[n][1]=y; sp[n][2]=z; sp[n][3]=0.0f;
      px[j]=x; py[j]=y; pz[j]=z; pd[j]=1e10f;
      *(f32x4*)(pxyz + ((long)b*4096+n)*4) = (f32x4){x,y,z,0.0f};
    }
    __threadfence();                             // pxyz visible device-wide
    if (tid==0){ sel[0]=0; cent[b*1024]=0; }
    __syncthreads();
    int f = 0;
    for (int t=1;t<1024;t++){
      f32x4 c = *(const f32x4*)sp[f];
      float bv=-1.0f; int bi=0;
#pragma unroll
      for (int j=0;j<16;j++){
        int n = tid + 256*j;
        float dx=px[j]-c[0], dy=py[j]-c[1], dz=pz[j]-c[2];
        float d=__fadd_rn(__fadd_rn(__fmul_rn(dx,dx),__fmul_rn(dy,dy)),__fmul_rn(dz,dz));
        float mn=fminf(pd[j],d); pd[j]=mn;
        if (j==0){ bv=mn; bi=n; }
        else if (mn>bv){ bv=mn; bi=n; }
      }
      u64 key = ((u64)__float_as_uint(bv)<<32) | (uint)(~bi);
#pragma unroll
      for (int off=32;off;off>>=1){
        u64 ok=__shfl_xor(key,off);
        key = ok>key ? ok : key;
      }
      int par=t&1;
      if (lane==0) rk[par*4+wave]=key;
      __syncthreads();
      {
        u64 k0=rk[par*4+0], k1=rk[par*4+1], k2=rk[par*4+2], k3=rk[par*4+3];
        u64 ka = k0>k1?k0:k1;
        u64 kb = k2>k3?k2:k3;
        u64 kk = ka>kb?ka:kb;
        f = (int)(~(uint)kk) & 4095;
      }
      if (tid==0){
        sel[t]=f;
        cent[b*1024+t]=f;
        if ((t&127)==127)
          __hip_atomic_store(&flags[b*8+(t>>7)], 1, __ATOMIC_RELEASE, __HIP_MEMORY_SCOPE_AGENT);
      }
    }
    __syncthreads();
#pragma unroll
    for (int j=0;j<4;j++){
      int s = tid + 256*j;
      int n = sel[s];
      f32x4 cf=*(const f32x4*)sp[n];
      oxyz[(b*1024+s)*3+0]=cf[0];
      oxyz[(b*1024+s)*3+1]=cf[1];
      oxyz[(b*1024+s)*3+2]=cf[2];
    }
  } else {
    // ---------------- KNN (stage-major ordering; r20 body on global pxyz) ----------------
    const int u = bid-16;                    // 0..4095
    const int st = u>>9;                     // stage 0..7 (512 blocks/stage)
    const int rem = u&511;
    const int b = rem>>5;                    // batch 0..15
    const int qb = st*128 + (rem&31)*4;      // first query of this block
    if (tid==0){
      while (__hip_atomic_load(&flags[b*8+st], __ATOMIC_ACQUIRE, __HIP_MEMORY_SCOPE_AGENT)==0)
        __builtin_amdgcn_s_sleep(64);
    }
    __syncthreads();
    const f32x4* __restrict__ P = (const f32x4*)pxyz + (long)b*4096;
    const int s = qb + wave;                 // one query per wave
    int qn = cent[b*1024 + s] & 4095;
    f32x4 Q = P[qn];
    double qx=(double)Q[0], qy=(double)Q[1], qz=(double)Q[2];
    u64 k1=SENT, k2=SENT;
#pragma unroll 4
    for (int j=0;j<64;j++){
      int n = lane + 64*j;
      f32x4 pt = P[n];
      double dx=(double)pt[0]-qx, dy=(double)pt[1]-qy, dz=(double)pt[2]-qz;
      double d2 = dx*dx + dy*dy + dz*dz;
      u64 kd = (((u64)__double_as_longlong(d2)) & ~4095ull) | (uint)n;
      if (kd<k1){ k2=k1; k1=kd; }
      else if (kd<k2){ k2=kd; }
    }
    u64 removed=0ull;
    ushort* outp = kidx + (b*1024 + s)*32;
    for (int r=0;r<32;r++){
      u64 wk=k1;
#pragma unroll
      for (int off=32;off;off>>=1){
        u64 ok=__shfl_xor(wk,off);
        wk = ok<wk ? ok : wk;
      }
      if (lane==0) outp[r]=(ushort)(wk & 4095u);
      if (wk==k1){
        removed |= 1ull << (((uint)(k1&4095u))>>6);
        if (k2!=SENT){ k1=k2; k2=SENT; }
        else {
          k1=SENT; k2=SENT;
#pragma unroll 4
          for (int j=0;j<64;j++){
            if ((removed>>j)&1ull) continue;
            int n = lane + 64*j;
            f32x4 pt = P[n];
            double dx=(double)pt[0]-qx, dy=(double)pt[1]-qy, dz=(double)pt[2]-qz;
            double d2 = dx*dx + dy*dy + dz*dz;
            u64 kd = (((u64)__double_as_longlong(d2)) & ~4095ull) | (uint)n;
            if (kd<k1){ k2=k1; k1=kd; }
            else if (kd<k2){ k2=kd; }
          }
        }
      }
    }
  }
}

// ================================================================ MFMA bf16 passes (r25/r26, passing)
// pass 1: gather -> bf16 -> MFMA x W1p -> stats + store raw y1
__global__ __launch_bounds__(256) void k_mlp1m(const float* __restrict__ xyz,
                                               const float* __restrict__ pts,
                                               const float* __restrict__ w1,
                                               const float* __restrict__ b1,
                                               const int* __restrict__ cent,
                                               const ushort* __restrict__ kidx,
                                               float* __restrict__ part,
                                               float* __restrict__ y){
  __shared__ __align__(16) ushort SA[128*STR1];   // 26.0 KB
  __shared__ __align__(16) ushort SW[64*STR1];    // 13.0 KB
  __shared__ float WRED[4*4*16*2];                // 2 KB
  const int tid=threadIdx.x, bi=blockIdx.x;
  const int lane=tid&63, wave=tid>>6;
  const int lo16=lane&15, hi16=lane>>4;
  const long bN=(long)(bi>>6)*4096;               // 64 blocks per batch

  for (int i=tid;i<64*96;i+=256){
    int r=i/96, c=i-r*96;
    float v = (c<64)? w1[r*67+3+c] : (c<67? w1[r*67+(c-64)] : 0.0f);
    SW[r*STR1+c]=bf1(v);
  }
  for (int i=tid;i<128*32;i+=256){
    int r=i>>5, c=64+(i&31);
    SA[r*STR1+c]=0;
  }
  const int ch4=(tid&15)*4, rb=(tid>>4)*8;
  float a1r[4];
#pragma unroll
  for (int nf=0;nf<4;nf++) a1r[nf]=b1[nf*16+lo16];
  float pss[4]={0.f,0.f,0.f,0.f}, pqq[4]={0.f,0.f,0.f,0.f};

  for (int t=0;t<4;t++){
    const long row0=(long)bi*512 + t*128;
    __syncthreads();
#pragma unroll
    for(int rr=0;rr<8;rr++){
      int r=rb+rr;
      long grow=row0+r;
      int n = kidx[grow] & 4095;
      f32x4 v=*(const f32x4*)(pts + (bN+n)*64 + ch4);
      uint2v pk; pk[0]=packbf2(v[0],v[1]); pk[1]=packbf2(v[2],v[3]);
      *(uint2v*)(SA+r*STR1+ch4)=pk;
    }
    if (tid<128){
      int r=tid;
      long grow=row0+r;
      int n = kidx[grow] & 4095;
      int q = cent[grow>>5] & 4095;
      const float* xp = xyz + (bN+n)*3;
      const float* qp = xyz + (bN+q)*3;
      SA[r*STR1+64]=bf1(xp[0]-qp[0]);
      SA[r*STR1+65]=bf1(xp[1]-qp[1]);
      SA[r*STR1+66]=bf1(xp[2]-qp[2]);
    }
    __syncthreads();
    const int mt=wave*32;
    f32x4 acc[2][4];
#pragma unroll
    for(int mf=0;mf<2;mf++)
#pragma unroll
      for(int nf=0;nf<4;nf++) acc[mf][nf]=(f32x4){0.f,0.f,0.f,0.f};
#pragma unroll
    for (int ks=0; ks<3; ks++){
      bf16x8 a0=*(const bf16x8*)(SA+(mt+lo16)*STR1    + ks*32 + hi16*8);
      bf16x8 a1f=*(const bf16x8*)(SA+(mt+16+lo16)*STR1 + ks*32 + hi16*8);
      bf16x8 b0=*(const bf16x8*)(SW+(lo16)*STR1     + ks*32 + hi16*8);
      bf16x8 b1f=*(const bf16x8*)(SW+(16+lo16)*STR1 + ks*32 + hi16*8);
      bf16x8 b2f=*(const bf16x8*)(SW+(32+lo16)*STR1 + ks*32 + hi16*8);
      bf16x8 b3f=*(const bf16x8*)(SW+(48+lo16)*STR1 + ks*32 + hi16*8);
      acc[0][0]=__builtin_amdgcn_mfma_f32_16x16x32_bf16(a0 ,b0 ,acc[0][0],0,0,0);
      acc[0][1]=__builtin_amdgcn_mfma_f32_16x16x32_bf16(a0 ,b1f,acc[0][1],0,0,0);
      acc[0][2]=__builtin_amdgcn_mfma_f32_16x16x32_bf16(a0 ,b2f,acc[0][2],0,0,0);
      acc[0][3]=__builtin_amdgcn_mfma_f32_16x16x32_bf16(a0 ,b3f,acc[0][3],0,0,0);
      acc[1][0]=__builtin_amdgcn_mfma_f32_16x16x32_bf16(a1f,b0 ,acc[1][0],0,0,0);
      acc[1][1]=__builtin_amdgcn_mfma_f32_16x16x32_bf16(a1f,b1f,acc[1][1],0,0,0);
      acc[1][2]=__builtin_amdgcn_mfma_f32_16x16x32_bf16(a1f,b2f,acc[1][2],0,0,0);
      acc[1][3]=__builtin_amdgcn_mfma_f32_16x16x32_bf16(a1f,b3f,acc[1][3],0,0,0);
    }
#pragma unroll
    for (int nf=0;nf<4;nf++){
#pragma unroll
      for (int mf=0;mf<2;mf++)
#pragma unroll
        for (int reg=0;reg<4;reg++){
          float d=acc[mf][nf][reg]+a1r[nf];
          long rr=row0+mt+mf*16+hi16*4+reg;
          y[rr*64 + nf*16+lo16]=d;
          pss[nf]+=d; pqq[nf]=fmaf(d,d,pqq[nf]);
        }
    }
  }
#pragma unroll
  for (int nf=0;nf<4;nf++){
    pss[nf]+=__shfl_xor(pss[nf],16); pss[nf]+=__shfl_xor(pss[nf],32);
    pqq[nf]+=__shfl_xor(pqq[nf],16); pqq[nf]+=__shfl_xor(pqq[nf],32);
  }
  if (lane<16){
#pragma unroll
    for (int nf=0;nf<4;nf++){
      WRED[((wave*4+nf)*16+lane)*2+0]=pss[nf];
      WRED[((wave*4+nf)*16+lane)*2+1]=pqq[nf];
    }
  }
  __syncthreads();
  if (tid<64){
    int ch=tid, nf=ch>>4, ci=ch&15;
    float s=0.f,q=0.f;
#pragma unroll
    for (int w=0;w<4;w++){ s+=WRED[((w*4+nf)*16+ci)*2]; q+=WRED[((w*4+nf)*16+ci)*2+1]; }
    part[(bi*64+ch)*2]=s; part[(bi*64+ch)*2+1]=q;
  }
}

// pass 2: y (fp32 y1) -> bn1+relu -> bf16 -> MFMA x W2 -> stats + store y2 fp32 in place
__global__ __launch_bounds__(256) void k_mlp2m(const float* __restrict__ w2,
                                               const float* __restrict__ b2,
                                               const float* __restrict__ ab1,
                                               float* __restrict__ part,
                                               float* __restrict__ y){
  __shared__ __align__(16) ushort SA[128*STR];    // 22.0 KB
  __shared__ __align__(16) ushort SW[64*STR];     // 11.0 KB
  __shared__ float WRED[4*4*16*2];                // 512 f
  const int tid=threadIdx.x, bi=blockIdx.x;
  const int lane=tid&63, wave=tid>>6;
  const int lo16=lane&15, hi16=lane>>4;

  for (int i=tid;i<4096;i+=256){
    int r=i>>6, c=i&63;
    SW[r*STR+c]=bf1(w2[i]);
  }
  const int ch4=(tid&15)*4, rb=(tid>>4)*8;
  float a1[4],c1[4];
#pragma unroll
  for(int j=0;j<4;j++){ a1[j]=ab1[(ch4+j)*2]; c1[j]=ab1[(ch4+j)*2+1]; }
  float bbn[4];
#pragma unroll
  for (int nf=0;nf<4;nf++) bbn[nf]=b2[nf*16+lo16];
  float pss[4]={0.f,0.f,0.f,0.f}, pqq[4]={0.f,0.f,0.f,0.f};

  for (int t=0;t<4;t++){
    const long row0=(long)bi*512 + t*128;
    __syncthreads();
#pragma unroll
    for(int rr=0;rr<8;rr++){
      int r=rb+rr;
      f32x4 v=*(const f32x4*)(y+(row0+r)*64+ch4);
      float x0=fmaxf(fmaf(a1[0],v[0],c1[0]),0.f);
      float x1=fmaxf(fmaf(a1[1],v[1],c1[1]),0.f);
      float x2=fmaxf(fmaf(a1[2],v[2],c1[2]),0.f);
      float x3=fmaxf(fmaf(a1[3],v[3],c1[3]),0.f);
      uint2v pk; pk[0]=packbf2(x0,x1); pk[1]=packbf2(x2,x3);
      *(uint2v*)(SA+r*STR+ch4)=pk;
    }
    __syncthreads();
    const int mt=wave*32;
    f32x4 acc[2][4];
#pragma unroll
    for(int mf=0;mf<2;mf++)
#pragma unroll
      for(int nf=0;nf<4;nf++) acc[mf][nf]=(f32x4){0.f,0.f,0.f,0.f};
#pragma unroll
    for (int ks=0; ks<2; ks++){
      bf16x8 a0=*(const bf16x8*)(SA+(mt+lo16)*STR    + ks*32 + hi16*8);
      bf16x8 a1f=*(const bf16x8*)(SA+(mt+16+lo16)*STR + ks*32 + hi16*8);
      bf16x8 b0=*(const bf16x8*)(SW+(lo16)*STR     + ks*32 + hi16*8);
      bf16x8 b1=*(const bf16x8*)(SW+(16+lo16)*STR  + ks*32 + hi16*8);
      bf16x8 b2f=*(const bf16x8*)(SW+(32+lo16)*STR + ks*32 + hi16*8);
      bf16x8 b3f=*(const bf16x8*)(SW+(48+lo16)*STR + ks*32 + hi16*8);
      acc[0][0]=__builtin_amdgcn_mfma_f32_16x16x32_bf16(a0 ,b0 ,acc[0][0],0,0,0);
      acc[0][1]=__builtin_amdgcn_mfma_f32_16x16x32_bf16(a0 ,b1 ,acc[0][1],0,0,0);
      acc[0][2]=__builtin_amdgcn_mfma_f32_16x16x32_bf16(a0 ,b2f,acc[0][2],0,0,0);
      acc[0][3]=__builtin_amdgcn_mfma_f32_16x16x32_bf16(a0 ,b3f,acc[0][3],0,0,0);
      acc[1][0]=__builtin_amdgcn_mfma_f32_16x16x32_bf16(a1f,b0 ,acc[1][0],0,0,0);
      acc[1][1]=__builtin_amdgcn_mfma_f32_16x16x32_bf16(a1f,b1 ,acc[1][1],0,0,0);
      acc[1][2]=__builtin_amdgcn_mfma_f32_16x16x32_bf16(a1f,b2f,acc[1][2],0,0,0);
      acc[1][3]=__builtin_amdgcn_mfma_f32_16x16x32_bf16(a1f,b3f,acc[1][3],0,0,0);
    }
#pragma unroll
    for (int nf=0;nf<4;nf++){
#pragma unroll
      for (int mf=0;mf<2;mf++)
#pragma unroll
        for (int reg=0;reg<4;reg++){
          float d=acc[mf][nf][reg]+bbn[nf];
          long rr=row0+mt+mf*16+hi16*4+reg;
          y[rr*64 + nf*16+lo16]=d;
          pss[nf]+=d; pqq[nf]=fmaf(d,d,pqq[nf]);
        }
    }
  }
#pragma unroll
  for (int nf=0;nf<4;nf++){
    pss[nf]+=__shfl_xor(pss[nf],16); pss[nf]+=__shfl_xor(pss[nf],32);
    pqq[nf]+=__shfl_xor(pqq[nf],16); pqq[nf]+=__shfl_xor(pqq[nf],32);
  }
  if (lane<16){
#pragma unroll
    for (int nf=0;nf<4;nf++){
      WRED[((wave*4+nf)*16+lane)*2+0]=pss[nf];
      WRED[((wave*4+nf)*16+lane)*2+1]=pqq[nf];
    }
  }
  __syncthreads();
  if (tid<64){
    int ch=tid, nf=ch>>4, ci=ch&15;
    float s=0.f,q=0.f;
#pragma unroll
    for (int w=0;w<4;w++){ s+=WRED[((w*4+nf)*16+ci)*2]; q+=WRED[((w*4+nf)*16+ci)*2+1]; }
    part[(bi*64+ch)*2]=s; part[(bi*64+ch)*2+1]=q;
  }
}

// pass 3: y (fp32 y2) -> bn2+relu -> bf16 -> MFMA x W3 -> stats + per-s maxpool -> mx
__global__ __launch_bounds__(256) void k_mlp3m(const float* __restrict__ w3,
                                               const float* __restrict__ b3,
                                               const float* __restrict__ ab2,
                                               float* __restrict__ part,
                                               const float* __restrict__ y,
                                               float* __restrict__ mx){
  __shared__ __align__(16) ushort SA[128*STR];    // 22.0 KB
  __shared__ __align__(16) ushort SW[128*STR];    // 22.0 KB
  __shared__ float WRED[4*8*16*2];                // 1024 f
  const int tid=threadIdx.x, bi=blockIdx.x;
  const int lane=tid&63, wave=tid>>6;
  const int lo16=lane&15, hi16=lane>>4;

  for (int i=tid;i<8192;i+=256){
    int r=i>>6, c=i&63;
    SW[r*STR+c]=bf1(w3[i]);
  }
  const int ch4=(tid&15)*4, rb=(tid>>4)*8;
  float a2[4],c2[4];
#pragma unroll
  for(int j=0;j<4;j++){ a2[j]=ab2[(ch4+j)*2]; c2[j]=ab2[(ch4+j)*2+1]; }
  float bbn[8];
#pragma unroll
  for (int nf=0;nf<8;nf++) bbn[nf]=b3[nf*16+lo16];
  float pss[8], pqq[8];
#pragma unroll
  for (int nf=0;nf<8;nf++){ pss[nf]=0.f; pqq[nf]=0.f; }

  for (int t=0;t<4;t++){
    const long row0=(long)bi*512 + t*128;
    __syncthreads();
#pragma unroll
    for(int rr=0;rr<8;rr++){
      int r=rb+rr;
      f32x4 v=*(const f32x4*)(y+(row0+r)*64+ch4);
      float x0=fmaxf(fmaf(a2[0],v[0],c2[0]),0.f);
      float x1=fmaxf(fmaf(a2[1],v[1],c2[1]),0.f);
      float x2=fmaxf(fmaf(a2[2],v[2],c2[2]),0.f);
      float x3=fmaxf(fmaf(a2[3],v[3],c2[3]),0.f);
      uint2v pk; pk[0]=packbf2(x0,x1); pk[1]=packbf2(x2,x3);
      *(uint2v*)(SA+r*STR+ch4)=pk;
    }
    __syncthreads();
    const int mt=wave*32;
    f32x4 acc[2][8];
#pragma unroll
    for(int mf=0;mf<2;mf++)
#pragma unroll
      for(int nf=0;nf<8;nf++) acc[mf][nf]=(f32x4){0.f,0.f,0.f,0.f};
#pragma unroll
    for (int ks=0; ks<2; ks++){
      bf16x8 a0=*(const bf16x8*)(SA+(mt+lo16)*STR    + ks*32 + hi16*8);
      bf16x8 a1f=*(const bf16x8*)(SA+(mt+16+lo16)*STR + ks*32 + hi16*8);
#pragma unroll
      for (int nf=0;nf<8;nf++){
        bf16x8 bv=*(const bf16x8*)(SW+(nf*16+lo16)*STR + ks*32 + hi16*8);
        acc[0][nf]=__builtin_amdgcn_mfma_f32_16x16x32_bf16(a0 ,bv,acc[0][nf],0,0,0);
        acc[1][nf]=__builtin_amdgcn_mfma_f32_16x16x32_bf16(a1f,bv,acc[1][nf],0,0,0);
      }
    }
    float vmx[8];
#pragma unroll
    for (int nf=0;nf<8;nf++) vmx[nf]=-3.0e38f;
#pragma unroll
    for (int nf=0;nf<8;nf++){
#pragma unroll
      for (int mf=0;mf<2;mf++)
#pragma unroll
        for (int reg=0;reg<4;reg++){
          float d=acc[mf][nf][reg]+bbn[nf];
          pss[nf]+=d; pqq[nf]=fmaf(d,d,pqq[nf]);
          vmx[nf]=fmaxf(vmx[nf],d);
        }
    }
#pragma unroll
    for (int nf=0;nf<8;nf++){
      vmx[nf]=fmaxf(vmx[nf],__shfl_xor(vmx[nf],16));
      vmx[nf]=fmaxf(vmx[nf],__shfl_xor(vmx[nf],32));
    }
    {
      long sg = (long)bi*16 + t*4 + wave;
      if (lane<16){
#pragma unroll
        for (int nf=0;nf<8;nf++) mx[sg*128 + nf*16 + lane]=vmx[nf];
      }
    }
  }
#pragma unroll
  for (int nf=0;nf<8;nf++){
    pss[nf]+=__shfl_xor(pss[nf],16); pss[nf]+=__shfl_xor(pss[nf],32);
    pqq[nf]+=__shfl_xor(pqq[nf],16); pqq[nf]+=__shfl_xor(pqq[nf],32);
  }
  if (lane<16){
#pragma unroll
    for (int nf=0;nf<8;nf++){
      WRED[((wave*8+nf)*16+lane)*2+0]=pss[nf];
      WRED[((wave*8+nf)*16+lane)*2+1]=pqq[nf];
    }
  }
  __syncthreads();
  if (tid<128){
    int ch=tid, nf=ch>>4, ci=ch&15;
    float s=0.f,q=0.f;
#pragma unroll
    for (int w=0;w<4;w++){ s+=WRED[((w*8+nf)*16+ci)*2]; q+=WRED[((w*8+nf)*16+ci)*2+1]; }
    part[(bi*128+ch)*2]=s; part[(bi*128+ch)*2+1]=q;
  }
}

// ---------------------------------------------------------------- stats finalize
__global__ void k_red(const float* __restrict__ part,
                      const float* __restrict__ gam,
                      const float* __restrict__ bet,
                      float* __restrict__ ab, int nch, int nblk){
  __shared__ float red[4][128][2];
  const int tid=threadIdx.x, ch=tid%nch, seg=tid/nch;
  float s=0.f,q=0.f;
  for (int i=seg;i<nblk;i+=4){ s+=part[(i*nch+ch)*2]; q+=part[(i*nch+ch)*2+1]; }
  red[seg][ch][0]=s; red[seg][ch][1]=q;
  __syncthreads();
  if (seg==0){
    s=red[0][ch][0]+red[1][ch][0]+red[2][ch][0]+red[3][ch][0];
    q=red[0][ch][1]+red[1][ch][1]+red[2][ch][1]+red[3][ch][1];
    float mu=s*(1.0f/524288.0f);
    float var=q*(1.0f/524288.0f)-mu*mu;
    var=fmaxf(var,0.0f);
    float a=gam[ch]/sqrtf(var+1e-5f);
    float c=bet[ch]-mu*a;
    ab[ch*2]=a; ab[ch*2+1]=c;
  }
}

// ---------------------------------------------------------------- final: onp = relu(a3*mx + c3)
__global__ __launch_bounds__(256) void k_out(const float* __restrict__ mx,
                                             const float* __restrict__ ab3,
                                             float* __restrict__ onp){
  int i = (blockIdx.x*256 + threadIdx.x)*4;   // 2048 blocks x 256 x 4 = 2,097,152
  int ch = i & 127;
  f32x4 v = *(const f32x4*)(mx+i);
  f32x4 r;
  r[0]=fmaxf(fmaf(ab3[(ch+0)*2], v[0], ab3[(ch+0)*2+1]), 0.0f);
  r[1]=fmaxf(fmaf(ab3[(ch+1)*2], v[1], ab3[(ch+1)*2+1]), 0.0f);
  r[2]=fmaxf(fmaf(ab3[(ch+2)*2], v[2], ab3[(ch+2)*2+1]), 0.0f);
  r[3]=fmaxf(fmaf(ab3[(ch+3)*2], v[3], ab3[(ch+3)*2+1]), 0.0f);
  *(f32x4*)(onp+i)=r;
}

// ---------------------------------------------------------------- host
extern "C" void kernel_launch(void* const* d_in, const int* in_sizes, int n_in,
                              void* d_out, int out_size, void* d_ws, size_t ws_size,
                              hipStream_t stream){
  const float* xyz=(const float*)d_in[0];
  const float* pts=(const float*)d_in[1];
  const float* w1 =(const float*)d_in[2];
  const float* b1 =(const float*)d_in[3];
  const float* g1 =(const float*)d_in[4];
  const float* be1=(const float*)d_in[5];
  const float* w2 =(const float*)d_in[6];
  const float* b2 =(const float*)d_in[7];
  const float* g2 =(const float*)d_in[8];
  const float* be2=(const float*)d_in[9];
  const float* w3 =(const float*)d_in[10];
  const float* b3 =(const float*)d_in[11];
  const float* g3 =(const float*)d_in[12];
  const float* be3=(const float*)d_in[13];
  char* ws=(char*)d_ws;
  int*    cent=(int*)(ws);                 //       0
  ushort* kidx=(ushort*)(ws+  65536);      //  +1 MB
  float*  p   =(float*)(ws+ 1114112);      //  +1 MB (stats, 1024 blk x <=128ch x 2)
  float*  ab1 =(float*)(ws+ 2162688);
  float*  ab2 =(float*)(ws+ 2163200);
  float*  ab3 =(float*)(ws+ 2163712);
  float*  mx  =(float*)(ws+ 2164736);      //  +8.4 MB -> ends ~10.06 MB
  float*  pxyz=(float*)(ws+11534336);      //  +1 MB padded points
  int*    flags=(int*)(ws+15728640);       //  128 ints of stage flags
  float*  y   =(float*)(ws+16777216);      //  +128 MB (r19 proved present)
  float* oxyz=(float*)d_out;
  float* onp =oxyz + 16*1024*3;

  hipMemsetAsync(flags, 0, 512, stream);
  k_fk<<<4112, 256, 0, stream>>>(xyz, cent, oxyz, pxyz, kidx, flags);
  k_mlp1m<<<1024, 256, 0, stream>>>(xyz, pts, w1, b1, cent, kidx, p, y);
  k_red<<<1, 256, 0, stream>>>(p, g1, be1, ab1, 64, 1024);
  k_mlp2m<<<1024, 256, 0, stream>>>(w2, b2, ab1, p, y);
  k_red<<<1, 256, 0, stream>>>(p, g2, be2, ab2, 64, 1024);
  k_mlp3m<<<1024, 256, 0, stream>>>(w3, b3, ab2, p, y, mx);
  k_red<<<1, 512, 0, stream>>>(p, g3, be3, ab3, 128, 1024);
  k_out<<<2048, 256, 0, stream>>>(mx, ab3, onp);
}

// Round 19
// 1693.037 us; speedup vs baseline: 1.2815x; 1.2815x over previous
//
#include <hip/hip_runtime.h>

typedef unsigned int   uint;
typedef unsigned short ushort;
typedef unsigned long long u64;
typedef float f32x4 __attribute__((ext_vector_type(4)));
typedef short bf16x8 __attribute__((ext_vector_type(8)));   // 8 bf16 = 4 VGPRs
typedef uint  uint2v __attribute__((ext_vector_type(2)));

#define STR  88    // LDS row stride (shorts) for 64-col tiles
#define STR1 104   // LDS row stride (shorts) for 96-col padded pass-1 tiles

// RNE fp32 -> bf16 pair packed into one dword
__device__ __forceinline__ uint packbf2(float a, float b){
  uint ua=__float_as_uint(a); ua=(ua+0x7fffu+((ua>>16)&1u))>>16;
  uint ub=__float_as_uint(b); ub=(ub+0x7fffu+((ub>>16)&1u))>>16;
  return ua|(ub<<16);
}
__device__ __forceinline__ ushort bf1(float a){
  uint ua=__float_as_uint(a); return (ushort)((ua+0x7fffu+((ua>>16)&1u))>>16);
}

// ---------------------------------------------------------------- FPS fp32
// r26 (session best, 1697us): dumps padded pxyz[4096][4] for knn. Selection
// arithmetic bit-locked to the reference FPS chain.
__global__ __launch_bounds__(256) void k_fps(const float* __restrict__ xyz,
                                             int* __restrict__ cent,
                                             float* __restrict__ oxyz,
                                             float* __restrict__ pxyz){
  __shared__ __align__(16) float sp[4096][4];   // 64 KB
  __shared__ u64 rk[2][4];
  __shared__ int sel[1024];                     // 4 KB
  const int b = blockIdx.x, tid = threadIdx.x, lane=tid&63, wave=tid>>6;
  const float* xb = xyz + (long)b*4096*3;
  float px[16], py[16], pz[16], pd[16];
#pragma unroll
  for (int j=0;j<16;j++){
    int n = tid + 256*j;
    float x=xb[n*3], y=xb[n*3+1], z=xb[n*3+2];
    sp[n][0]=x; sp[n][1]=y; sp[n][2]=z; sp[n][3]=0.0f;
    px[j]=x; py[j]=y; pz[j]=z; pd[j]=1e10f;
  }
  if (tid==0) sel[0]=0;
  __syncthreads();
  int f = 0;
  for (int t=1;t<1024;t++){
    f32x4 c = *(const f32x4*)sp[f];
    float bv=-1.0f; int bi=0;
#pragma unroll
    for (int j=0;j<16;j++){
      int n = tid + 256*j;
      float dx=px[j]-c[0], dy=py[j]-c[1], dz=pz[j]-c[2];
      float d=__fadd_rn(__fadd_rn(__fmul_rn(dx,dx),__fmul_rn(dy,dy)),__fmul_rn(dz,dz));
      float mn=fminf(pd[j],d); pd[j]=mn;
      if (j==0){ bv=mn; bi=n; }
      else if (mn>bv){ bv=mn; bi=n; }
    }
    u64 key = ((u64)__float_as_uint(bv)<<32) | (uint)(~bi);
#pragma unroll
    for (int off=32;off;off>>=1){
      u64 ok=__shfl_xor(key,off);
      key = ok>key ? ok : key;
    }
    int par=t&1;
    if (lane==0) rk[par][wave]=key;
    __syncthreads();
    {
      u64 k0=rk[par][0], k1=rk[par][1], k2=rk[par][2], k3=rk[par][3];
      u64 ka = k0>k1?k0:k1;
      u64 kb = k2>k3?k2:k3;
      u64 kk = ka>kb?ka:kb;
      f = (int)(~(uint)kk) & 4095;
    }
    if (tid==0) sel[t]=f;
  }
  __syncthreads();
#pragma unroll
  for (int j=0;j<4;j++){
    int s = tid + 256*j;
    int n = sel[s];
    cent[b*1024+s]=n;
    f32x4 cf=*(const f32x4*)sp[n];
    oxyz[(b*1024+s)*3+0]=cf[0];
    oxyz[(b*1024+s)*3+1]=cf[1];
    oxyz[(b*1024+s)*3+2]=cf[2];
  }
  // dump padded point array for knn (coalesced dwordx4)
#pragma unroll
  for (int j=0;j<16;j++){
    int n = tid + 256*j;
    *(f32x4*)(pxyz + ((long)b*4096+n)*4) = *(const f32x4*)sp[n];
  }
}

// ---------------------------------------------------------------- KNN
// r26: zero-LDS. Scans + rescans read pxyz (L2-hot) via f32x4 loads;
// extraction shfls are the only DS ops. Values identical to staged floats
// -> bit-identical selection. 1024 blocks, 4 blocks/CU.
__global__ __launch_bounds__(256) void k_knn(const float* __restrict__ pxyz,
                                             const int* __restrict__ cent,
                                             ushort* __restrict__ kidx){
  const int bx=blockIdx.x, b=bx>>6, hc=bx&63;
  const int tid=threadIdx.x, lane=tid&63, wave=tid>>6;
  const f32x4* __restrict__ P = (const f32x4*)pxyz + (long)b*4096;
  const u64 SENT=~0ull;
  for (int qp=0; qp<2; qp++){
    int sA = hc*16 + wave*4 + qp*2;
    int sB = sA + 1;
    int qnA = cent[b*1024 + sA] & 4095;
    int qnB = cent[b*1024 + sB] & 4095;
    f32x4 QA = P[qnA], QB = P[qnB];
    double qxA=(double)QA[0], qyA=(double)QA[1], qzA=(double)QA[2];
    double qxB=(double)QB[0], qyB=(double)QB[1], qzB=(double)QB[2];
    u64 k1A=SENT, k2A=SENT, k1B=SENT, k2B=SENT;
#pragma unroll 4
    for (int j=0;j<64;j++){
      int n = lane + 64*j;
      f32x4 pt = P[n];
      double px=(double)pt[0], py=(double)pt[1], pz=(double)pt[2];
      double dxA=px-qxA, dyA=py-qyA, dzA=pz-qzA;
      double dxB=px-qxB, dyB=py-qyB, dzB=pz-qzB;
      double d2A = dxA*dxA + dyA*dyA + dzA*dzA;
      double d2B = dxB*dxB + dyB*dyB + dzB*dzB;
      u64 kdA = (((u64)__double_as_longlong(d2A)) & ~4095ull) | (uint)n;
      u64 kdB = (((u64)__double_as_longlong(d2B)) & ~4095ull) | (uint)n;
      if (kdA<k1A){ k2A=k1A; k1A=kdA; }
      else if (kdA<k2A){ k2A=kdA; }
      if (kdB<k1B){ k2B=k1B; k1B=kdB; }
      else if (kdB<k2B){ k2B=kdB; }
    }
    u64 removedA=0ull, removedB=0ull;
    ushort* outA = kidx + (b*1024 + sA)*32;
    ushort* outB = kidx + (b*1024 + sB)*32;
    for (int r=0;r<32;r++){
      u64 wkA=k1A, wkB=k1B;
#pragma unroll
      for (int off=32;off;off>>=1){
        u64 okA=__shfl_xor(wkA,off);
        u64 okB=__shfl_xor(wkB,off);
        wkA = okA<wkA ? okA : wkA;
        wkB = okB<wkB ? okB : wkB;
      }
      if (lane==0){ outA[r]=(ushort)(wkA & 4095u); outB[r]=(ushort)(wkB & 4095u); }
      if (wkA==k1A){
        removedA |= 1ull << (((uint)(k1A&4095u))>>6);
        if (k2A!=SENT){ k1A=k2A; k2A=SENT; }
        else {
          k1A=SENT; k2A=SENT;
#pragma unroll 4
          for (int j=0;j<64;j++){
            if ((removedA>>j)&1ull) continue;
            int n = lane + 64*j;
            f32x4 pt = P[n];
            double dx=(double)pt[0]-qxA, dy=(double)pt[1]-qyA, dz=(double)pt[2]-qzA;
            double d2 = dx*dx + dy*dy + dz*dz;
            u64 kd = (((u64)__double_as_longlong(d2)) & ~4095ull) | (uint)n;
            if (kd<k1A){ k2A=k1A; k1A=kd; }
            else if (kd<k2A){ k2A=kd; }
          }
        }
      }
      if (wkB==k1B){
        removedB |= 1ull << (((uint)(k1B&4095u))>>6);
        if (k2B!=SENT){ k1B=k2B; k2B=SENT; }
        else {
          k1B=SENT; k2B=SENT;
#pragma unroll 4
          for (int j=0;j<64;j++){
            if ((removedB>>j)&1ull) continue;
            int n = lane + 64*j;
            f32x4 pt = P[n];
            double dx=(double)pt[0]-qxB, dy=(double)pt[1]-qyB, dz=(double)pt[2]-qzB;
            double d2 = dx*dx + dy*dy + dz*dz;
            u64 kd = (((u64)__double_as_longlong(d2)) & ~4095ull) | (uint)n;
            if (kd<k1B){ k2B=k1B; k1B=kd; }
            else if (kd<k2B){ k2B=kd; }
          }
        }
      }
    }
  }
}

// ================================================================ MFMA bf16 passes (r25/r26, passing)
// pass 1: gather -> bf16 -> MFMA x W1p -> stats + store raw y1
__global__ __launch_bounds__(256) void k_mlp1m(const float* __restrict__ xyz,
                                               const float* __restrict__ pts,
                                               const float* __restrict__ w1,
                                               const float* __restrict__ b1,
                                               const int* __restrict__ cent,
                                               const ushort* __restrict__ kidx,
                                               float* __restrict__ part,
                                               float* __restrict__ y){
  __shared__ __align__(16) ushort SA[128*STR1];   // 26.0 KB
  __shared__ __align__(16) ushort SW[64*STR1];    // 13.0 KB
  __shared__ float WRED[4*4*16*2];                // 2 KB
  const int tid=threadIdx.x, bi=blockIdx.x;
  const int lane=tid&63, wave=tid>>6;
  const int lo16=lane&15, hi16=lane>>4;
  const long bN=(long)(bi>>6)*4096;               // 64 blocks per batch

  for (int i=tid;i<64*96;i+=256){
    int r=i/96, c=i-r*96;
    float v = (c<64)? w1[r*67+3+c] : (c<67? w1[r*67+(c-64)] : 0.0f);
    SW[r*STR1+c]=bf1(v);
  }
  for (int i=tid;i<128*32;i+=256){
    int r=i>>5, c=64+(i&31);
    SA[r*STR1+c]=0;
  }
  const int ch4=(tid&15)*4, rb=(tid>>4)*8;
  float a1r[4];
#pragma unroll
  for (int nf=0;nf<4;nf++) a1r[nf]=b1[nf*16+lo16];
  float pss[4]={0.f,0.f,0.f,0.f}, pqq[4]={0.f,0.f,0.f,0.f};

  for (int t=0;t<4;t++){
    const long row0=(long)bi*512 + t*128;
    __syncthreads();
#pragma unroll
    for(int rr=0;rr<8;rr++){
      int r=rb+rr;
      long grow=row0+r;
      int n = kidx[grow] & 4095;
      f32x4 v=*(const f32x4*)(pts + (bN+n)*64 + ch4);
      uint2v pk; pk[0]=packbf2(v[0],v[1]); pk[1]=packbf2(v[2],v[3]);
      *(uint2v*)(SA+r*STR1+ch4)=pk;
    }
    if (tid<128){
      int r=tid;
      long grow=row0+r;
      int n = kidx[grow] & 4095;
      int q = cent[grow>>5] & 4095;
      const float* xp = xyz + (bN+n)*3;
      const float* qp = xyz + (bN+q)*3;
      SA[r*STR1+64]=bf1(xp[0]-qp[0]);
      SA[r*STR1+65]=bf1(xp[1]-qp[1]);
      SA[r*STR1+66]=bf1(xp[2]-qp[2]);
    }
    __syncthreads();
    const int mt=wave*32;
    f32x4 acc[2][4];
#pragma unroll
    for(int mf=0;mf<2;mf++)
#pragma unroll
      for(int nf=0;nf<4;nf++) acc[mf][nf]=(f32x4){0.f,0.f,0.f,0.f};
#pragma unroll
    for (int ks=0; ks<3; ks++){
      bf16x8 a0=*(const bf16x8*)(SA+(mt+lo16)*STR1    + ks*32 + hi16*8);
      bf16x8 a1f=*(const bf16x8*)(SA+(mt+16+lo16)*STR1 + ks*32 + hi16*8);
      bf16x8 b0=*(const bf16x8*)(SW+(lo16)*STR1     + ks*32 + hi16*8);
      bf16x8 b1f=*(const bf16x8*)(SW+(16+lo16)*STR1 + ks*32 + hi16*8);
      bf16x8 b2f=*(const bf16x8*)(SW+(32+lo16)*STR1 + ks*32 + hi16*8);
      bf16x8 b3f=*(const bf16x8*)(SW+(48+lo16)*STR1 + ks*32 + hi16*8);
      acc[0][0]=__builtin_amdgcn_mfma_f32_16x16x32_bf16(a0 ,b0 ,acc[0][0],0,0,0);
      acc[0][1]=__builtin_amdgcn_mfma_f32_16x16x32_bf16(a0 ,b1f,acc[0][1],0,0,0);
      acc[0][2]=__builtin_amdgcn_mfma_f32_16x16x32_bf16(a0 ,b2f,acc[0][2],0,0,0);
      acc[0][3]=__builtin_amdgcn_mfma_f32_16x16x32_bf16(a0 ,b3f,acc[0][3],0,0,0);
      acc[1][0]=__builtin_amdgcn_mfma_f32_16x16x32_bf16(a1f,b0 ,acc[1][0],0,0,0);
      acc[1][1]=__builtin_amdgcn_mfma_f32_16x16x32_bf16(a1f,b1f,acc[1][1],0,0,0);
      acc[1][2]=__builtin_amdgcn_mfma_f32_16x16x32_bf16(a1f,b2f,acc[1][2],0,0,0);
      acc[1][3]=__builtin_amdgcn_mfma_f32_16x16x32_bf16(a1f,b3f,acc[1][3],0,0,0);
    }
#pragma unroll
    for (int nf=0;nf<4;nf++){
#pragma unroll
      for (int mf=0;mf<2;mf++)
#pragma unroll
        for (int reg=0;reg<4;reg++){
          float d=acc[mf][nf][reg]+a1r[nf];
          long rr=row0+mt+mf*16+hi16*4+reg;
          y[rr*64 + nf*16+lo16]=d;
          pss[nf]+=d; pqq[nf]=fmaf(d,d,pqq[nf]);
        }
    }
  }
#pragma unroll
  for (int nf=0;nf<4;nf++){
    pss[nf]+=__shfl_xor(pss[nf],16); pss[nf]+=__shfl_xor(pss[nf],32);
    pqq[nf]+=__shfl_xor(pqq[nf],16); pqq[nf]+=__shfl_xor(pqq[nf],32);
  }
  if (lane<16){
#pragma unroll
    for (int nf=0;nf<4;nf++){
      WRED[((wave*4+nf)*16+lane)*2+0]=pss[nf];
      WRED[((wave*4+nf)*16+lane)*2+1]=pqq[nf];
    }
  }
  __syncthreads();
  if (tid<64){
    int ch=tid, nf=ch>>4, ci=ch&15;
    float s=0.f,q=0.f;
#pragma unroll
    for (int w=0;w<4;w++){ s+=WRED[((w*4+nf)*16+ci)*2]; q+=WRED[((w*4+nf)*16+ci)*2+1]; }
    part[(bi*64+ch)*2]=s; part[(bi*64+ch)*2+1]=q;
  }
}

// pass 2: y (fp32 y1) -> bn1+relu -> bf16 -> MFMA x W2 -> stats + store y2 fp32 in place
__global__ __launch_bounds__(256) void k_mlp2m(const float* __restrict__ w2,
                                               const float* __restrict__ b2,
                                               const float* __restrict__ ab1,
                                               float* __restrict__ part,
                                               float* __restrict__ y){
  __shared__ __align__(16) ushort SA[128*STR];    // 22.0 KB
  __shared__ __align__(16) ushort SW[64*STR];     // 11.0 KB
  __shared__ float WRED[4*4*16*2];                // 512 f
  const int tid=threadIdx.x, bi=blockIdx.x;
  const int lane=tid&63, wave=tid>>6;
  const int lo16=lane&15, hi16=lane>>4;

  for (int i=tid;i<4096;i+=256){
    int r=i>>6, c=i&63;
    SW[r*STR+c]=bf1(w2[i]);
  }
  const int ch4=(tid&15)*4, rb=(tid>>4)*8;
  float a1[4],c1[4];
#pragma unroll
  for(int j=0;j<4;j++){ a1[j]=ab1[(ch4+j)*2]; c1[j]=ab1[(ch4+j)*2+1]; }
  float bbn[4];
#pragma unroll
  for (int nf=0;nf<4;nf++) bbn[nf]=b2[nf*16+lo16];
  float pss[4]={0.f,0.f,0.f,0.f}, pqq[4]={0.f,0.f,0.f,0.f};

  for (int t=0;t<4;t++){
    const long row0=(long)bi*512 + t*128;
    __syncthreads();
#pragma unroll
    for(int rr=0;rr<8;rr++){
      int r=rb+rr;
      f32x4 v=*(const f32x4*)(y+(row0+r)*64+ch4);
      float x0=fmaxf(fmaf(a1[0],v[0],c1[0]),0.f);
      float x1=fmaxf(fmaf(a1[1],v[1],c1[1]),0.f);
      float x2=fmaxf(fmaf(a1[2],v[2],c1[2]),0.f);
      float x3=fmaxf(fmaf(a1[3],v[3],c1[3]),0.f);
      uint2v pk; pk[0]=packbf2(x0,x1); pk[1]=packbf2(x2,x3);
      *(uint2v*)(SA+r*STR+ch4)=pk;
    }
    __syncthreads();
    const int mt=wave*32;
    f32x4 acc[2][4];
#pragma unroll
    for(int mf=0;mf<2;mf++)
#pragma unroll
      for(int nf=0;nf<4;nf++) acc[mf][nf]=(f32x4){0.f,0.f,0.f,0.f};
#pragma unroll
    for (int ks=0; ks<2; ks++){
      bf16x8 a0=*(const bf16x8*)(SA+(mt+lo16)*STR    + ks*32 + hi16*8);
      bf16x8 a1f=*(const bf16x8*)(SA+(mt+16+lo16)*STR + ks*32 + hi16*8);
      bf16x8 b0=*(const bf16x8*)(SW+(lo16)*STR     + ks*32 + hi16*8);
      bf16x8 b1=*(const bf16x8*)(SW+(16+lo16)*STR  + ks*32 + hi16*8);
      bf16x8 b2f=*(const bf16x8*)(SW+(32+lo16)*STR + ks*32 + hi16*8);
      bf16x8 b3f=*(const bf16x8*)(SW+(48+lo16)*STR + ks*32 + hi16*8);
      acc[0][0]=__builtin_amdgcn_mfma_f32_16x16x32_bf16(a0 ,b0 ,acc[0][0],0,0,0);
      acc[0][1]=__builtin_amdgcn_mfma_f32_16x16x32_bf16(a0 ,b1 ,acc[0][1],0,0,0);
      acc[0][2]=__builtin_amdgcn_mfma_f32_16x16x32_bf16(a0 ,b2f,acc[0][2],0,0,0);
      acc[0][3]=__builtin_amdgcn_mfma_f32_16x16x32_bf16(a0 ,b3f,acc[0][3],0,0,0);
      acc[1][0]=__builtin_amdgcn_mfma_f32_16x16x32_bf16(a1f,b0 ,acc[1][0],0,0,0);
      acc[1][1]=__builtin_amdgcn_mfma_f32_16x16x32_bf16(a1f,b1 ,acc[1][1],0,0,0);
      acc[1][2]=__builtin_amdgcn_mfma_f32_16x16x32_bf16(a1f,b2f,acc[1][2],0,0,0);
      acc[1][3]=__builtin_amdgcn_mfma_f32_16x16x32_bf16(a1f,b3f,acc[1][3],0,0,0);
    }
#pragma unroll
    for (int nf=0;nf<4;nf++){
#pragma unroll
      for (int mf=0;mf<2;mf++)
#pragma unroll
        for (int reg=0;reg<4;reg++){
          float d=acc[mf][nf][reg]+bbn[nf];
          long rr=row0+mt+mf*16+hi16*4+reg;
          y[rr*64 + nf*16+lo16]=d;
          pss[nf]+=d; pqq[nf]=fmaf(d,d,pqq[nf]);
        }
    }
  }
#pragma unroll
  for (int nf=0;nf<4;nf++){
    pss[nf]+=__shfl_xor(pss[nf],16); pss[nf]+=__shfl_xor(pss[nf],32);
    pqq[nf]+=__shfl_xor(pqq[nf],16); pqq[nf]+=__shfl_xor(pqq[nf],32);
  }
  if (lane<16){
#pragma unroll
    for (int nf=0;nf<4;nf++){
      WRED[((wave*4+nf)*16+lane)*2+0]=pss[nf];
      WRED[((wave*4+nf)*16+lane)*2+1]=pqq[nf];
    }
  }
  __syncthreads();
  if (tid<64){
    int ch=tid, nf=ch>>4, ci=ch&15;
    float s=0.f,q=0.f;
#pragma unroll
    for (int w=0;w<4;w++){ s+=WRED[((w*4+nf)*16+ci)*2]; q+=WRED[((w*4+nf)*16+ci)*2+1]; }
    part[(bi*64+ch)*2]=s; part[(bi*64+ch)*2+1]=q;
  }
}

// pass 3: y (fp32 y2) -> bn2+relu -> bf16 -> MFMA x W3 -> stats + per-s maxpool -> mx
__global__ __launch_bounds__(256) void k_mlp3m(const float* __restrict__ w3,
                                               const float* __restrict__ b3,
                                               const float* __restrict__ ab2,
                                               float* __restrict__ part,
                                               const float* __restrict__ y,
                                               float* __restrict__ mx){
  __shared__ __align__(16) ushort SA[128*STR];    // 22.0 KB
  __shared__ __align__(16) ushort SW[128*STR];    // 22.0 KB
  __shared__ float WRED[4*8*16*2];                // 1024 f
  const int tid=threadIdx.x, bi=blockIdx.x;
  const int lane=tid&63, wave=tid>>6;
  const int lo16=lane&15, hi16=lane>>4;

  for (int i=tid;i<8192;i+=256){
    int r=i>>6, c=i&63;
    SW[r*STR+c]=bf1(w3[i]);
  }
  const int ch4=(tid&15)*4, rb=(tid>>4)*8;
  float a2[4],c2[4];
#pragma unroll
  for(int j=0;j<4;j++){ a2[j]=ab2[(ch4+j)*2]; c2[j]=ab2[(ch4+j)*2+1]; }
  float bbn[8];
#pragma unroll
  for (int nf=0;nf<8;nf++) bbn[nf]=b3[nf*16+lo16];
  float pss[8], pqq[8];
#pragma unroll
  for (int nf=0;nf<8;nf++){ pss[nf]=0.f; pqq[nf]=0.f; }

  for (int t=0;t<4;t++){
    const long row0=(long)bi*512 + t*128;
    __syncthreads();
#pragma unroll
    for(int rr=0;rr<8;rr++){
      int r=rb+rr;
      f32x4 v=*(const f32x4*)(y+(row0+r)*64+ch4);
      float x0=fmaxf(fmaf(a2[0],v[0],c2[0]),0.f);
      float x1=fmaxf(fmaf(a2[1],v[1],c2[1]),0.f);
      float x2=fmaxf(fmaf(a2[2],v[2],c2[2]),0.f);
      float x3=fmaxf(fmaf(a2[3],v[3],c2[3]),0.f);
      uint2v pk; pk[0]=packbf2(x0,x1); pk[1]=packbf2(x2,x3);
      *(uint2v*)(SA+r*STR+ch4)=pk;
    }
    __syncthreads();
    const int mt=wave*32;
    f32x4 acc[2][8];
#pragma unroll
    for(int mf=0;mf<2;mf++)
#pragma unroll
      for(int nf=0;nf<8;nf++) acc[mf][nf]=(f32x4){0.f,0.f,0.f,0.f};
#pragma unroll
    for (int ks=0; ks<2; ks++){
      bf16x8 a0=*(const bf16x8*)(SA+(mt+lo16)*STR    + ks*32 + hi16*8);
      bf16x8 a1f=*(const bf16x8*)(SA+(mt+16+lo16)*STR + ks*32 + hi16*8);
#pragma unroll
      for (int nf=0;nf<8;nf++){
        bf16x8 bv=*(const bf16x8*)(SW+(nf*16+lo16)*STR + ks*32 + hi16*8);
        acc[0][nf]=__builtin_amdgcn_mfma_f32_16x16x32_bf16(a0 ,bv,acc[0][nf],0,0,0);
        acc[1][nf]=__builtin_amdgcn_mfma_f32_16x16x32_bf16(a1f,bv,acc[1][nf],0,0,0);
      }
    }
    float vmx[8];
#pragma unroll
    for (int nf=0;nf<8;nf++) vmx[nf]=-3.0e38f;
#pragma unroll
    for (int nf=0;nf<8;nf++){
#pragma unroll
      for (int mf=0;mf<2;mf++)
#pragma unroll
        for (int reg=0;reg<4;reg++){
          float d=acc[mf][nf][reg]+bbn[nf];
          pss[nf]+=d; pqq[nf]=fmaf(d,d,pqq[nf]);
          vmx[nf]=fmaxf(vmx[nf],d);
        }
    }
#pragma unroll
    for (int nf=0;nf<8;nf++){
      vmx[nf]=fmaxf(vmx[nf],__shfl_xor(vmx[nf],16));
      vmx[nf]=fmaxf(vmx[nf],__shfl_xor(vmx[nf],32));
    }
    {
      long sg = (long)bi*16 + t*4 + wave;
      if (lane<16){
#pragma unroll
        for (int nf=0;nf<8;nf++) mx[sg*128 + nf*16 + lane]=vmx[nf];
      }
    }
  }
#pragma unroll
  for (int nf=0;nf<8;nf++){
    pss[nf]+=__shfl_xor(pss[nf],16); pss[nf]+=__shfl_xor(pss[nf],32);
    pqq[nf]+=__shfl_xor(pqq[nf],16); pqq[nf]+=__shfl_xor(pqq[nf],32);
  }
  if (lane<16){
#pragma unroll
    for (int nf=0;nf<8;nf++){
      WRED[((wave*8+nf)*16+lane)*2+0]=pss[nf];
      WRED[((wave*8+nf)*16+lane)*2+1]=pqq[nf];
    }
  }
  __syncthreads();
  if (tid<128){
    int ch=tid, nf=ch>>4, ci=ch&15;
    float s=0.f,q=0.f;
#pragma unroll
    for (int w=0;w<4;w++){ s+=WRED[((w*8+nf)*16+ci)*2]; q+=WRED[((w*8+nf)*16+ci)*2+1]; }
    part[(bi*128+ch)*2]=s; part[(bi*128+ch)*2+1]=q;
  }
}

// ---------------------------------------------------------------- stats finalize
__global__ void k_red(const float* __restrict__ part,
                      const float* __restrict__ gam,
                      const float* __restrict__ bet,
                      float* __restrict__ ab, int nch, int nblk){
  __shared__ float red[4][128][2];
  const int tid=threadIdx.x, ch=tid%nch, seg=tid/nch;
  float s=0.f,q=0.f;
  for (int i=seg;i<nblk;i+=4){ s+=part[(i*nch+ch)*2]; q+=part[(i*nch+ch)*2+1]; }
  red[seg][ch][0]=s; red[seg][ch][1]=q;
  __syncthreads();
  if (seg==0){
    s=red[0][ch][0]+red[1][ch][0]+red[2][ch][0]+red[3][ch][0];
    q=red[0][ch][1]+red[1][ch][1]+red[2][ch][1]+red[3][ch][1];
    float mu=s*(1.0f/524288.0f);
    float var=q*(1.0f/524288.0f)-mu*mu;
    var=fmaxf(var,0.0f);
    float a=gam[ch]/sqrtf(var+1e-5f);
    float c=bet[ch]-mu*a;
    ab[ch*2]=a; ab[ch*2+1]=c;
  }
}

// ---------------------------------------------------------------- final: onp = relu(a3*mx + c3)
__global__ __launch_bounds__(256) void k_out(const float* __restrict__ mx,
                                             const float* __restrict__ ab3,
                                             float* __restrict__ onp){
  int i = (blockIdx.x*256 + threadIdx.x)*4;   // 2048 blocks x 256 x 4 = 2,097,152
  int ch = i & 127;
  f32x4 v = *(const f32x4*)(mx+i);
  f32x4 r;
  r[0]=fmaxf(fmaf(ab3[(ch+0)*2], v[0], ab3[(ch+0)*2+1]), 0.0f);
  r[1]=fmaxf(fmaf(ab3[(ch+1)*2], v[1], ab3[(ch+1)*2+1]), 0.0f);
  r[2]=fmaxf(fmaf(ab3[(ch+2)*2], v[2], ab3[(ch+2)*2+1]), 0.0f);
  r[3]=fmaxf(fmaf(ab3[(ch+3)*2], v[3], ab3[(ch+3)*2+1]), 0.0f);
  *(f32x4*)(onp+i)=r;
}

// ---------------------------------------------------------------- host
extern "C" void kernel_launch(void* const* d_in, const int* in_sizes, int n_in,
                              void* d_out, int out_size, void* d_ws, size_t ws_size,
                              hipStream_t stream){
  const float* xyz=(const float*)d_in[0];
  const float* pts=(const float*)d_in[1];
  const float* w1 =(const float*)d_in[2];
  const float* b1 =(const float*)d_in[3];
  const float* g1 =(const float*)d_in[4];
  const float* be1=(const float*)d_in[5];
  const float* w2 =(const float*)d_in[6];
  const float* b2 =(const float*)d_in[7];
  const float* g2 =(const float*)d_in[8];
  const float* be2=(const float*)d_in[9];
  const float* w3 =(const float*)d_in[10];
  const float* b3 =(const float*)d_in[11];
  const float* g3 =(const float*)d_in[12];
  const float* be3=(const float*)d_in[13];
  char* ws=(char*)d_ws;
  int*    cent=(int*)(ws);                 //       0
  ushort* kidx=(ushort*)(ws+  65536);      //  +1 MB
  float*  p   =(float*)(ws+ 1114112);      //  +1 MB (stats, 1024 blk x <=128ch x 2)
  float*  ab1 =(float*)(ws+ 2162688);
  float*  ab2 =(float*)(ws+ 2163200);
  float*  ab3 =(float*)(ws+ 2163712);
  float*  mx  =(float*)(ws+ 2164736);      //  +8.4 MB -> ends ~10.06 MB
  float*  pxyz=(float*)(ws+11534336);      //  +1 MB padded points [11,12) MB (proven region)
  float*  y   =(float*)(ws+16777216);      //  +128 MB (r19 proved present)
  float* oxyz=(float*)d_out;
  float* onp =oxyz + 16*1024*3;

  k_fps<<<16, 256, 0, stream>>>(xyz, cent, oxyz, pxyz);
  k_knn<<<1024, 256, 0, stream>>>(pxyz, cent, kidx);
  k_mlp1m<<<1024, 256, 0, stream>>>(xyz, pts, w1, b1, cent, kidx, p, y);
  k_red<<<1, 256, 0, stream>>>(p, g1, be1, ab1, 64, 1024);
  k_mlp2m<<<1024, 256, 0, stream>>>(w2, b2, ab1, p, y);
  k_red<<<1, 256, 0, stream>>>(p, g2, be2, ab2, 64, 1024);
  k_mlp3m<<<1024, 256, 0, stream>>>(w3, b3, ab2, p, y, mx);
  k_red<<<1, 512, 0, stream>>>(p, g3, be3, ab3, 128, 1024);
  k_out<<<2048, 256, 0, stream>>>(mx, ab3, onp);
}